// Round 6
// baseline (129.836 us; speedup 1.0000x reference)
//
#include <hip/hip_runtime.h>
#include <hip/hip_bf16.h>

// Problem dims (fixed by the reference setup_inputs)
#define BB 8
#define TT 4096
#define SS 256
#define DD 512

typedef __attribute__((ext_vector_type(8))) short short8;
typedef __attribute__((ext_vector_type(4))) float floatx4;
typedef __attribute__((ext_vector_type(4))) int intx4;

// Packed RNE f32x2 -> bf16x2 (v_cvt_pk_bf16_f32 on gfx950).
__device__ inline int pk2(float a, float b) {
  __hip_bfloat162 h = __float22bfloat162_rn(make_float2(a, b));
  int r;
  __builtin_memcpy(&r, &h, 4);
  return r;
}

// Pack 8 consecutive-k f32 values into a bf16 MFMA fragment.
__device__ inline short8 cvt8(float4 f0, float4 f1) {
  intx4 p;
  p[0] = pk2(f0.x, f0.y);
  p[1] = pk2(f0.z, f0.w);
  p[2] = pk2(f1.x, f1.y);
  p[3] = pk2(f1.z, f1.w);
  return __builtin_bit_cast(short8, p);
}

// SINGLE fused cosine scorer (round 5 resubmit; round-5 bench was an
// infra failure, kernel never ran): verified R1 structure — 128x128
// tile, 4 waves (2x2), per-wave 64x64, A f32 staged via global_load_lds
// w=16 with XOR-16 swizzle, double-buffered, ONE barrier per kt, XCD
// swizzle (XCD x owns batch b==x, tn-pairs adjacent), gram-MFMA norms,
// identical accumulation order — with the former packB kernel FOLDED IN:
// B fragments are built in-register from spk f32 (16 global_load_dwordx4
// + 16 cvt8 per kt per wave, element-for-element the K1 fragment layout:
// lane l holds row ...+(l&15), k = kt*64+ks*32+(l>>4)*8..+8). spk is
// 4 MiB -> L2-resident per XCD after first touch, so the extra B-side
// VMEM is noise. This removes ALL workspace usage (the 2x256 MiB ws
// poison fills are 71% of the measured window) and the second launch.
__global__ __launch_bounds__(256) void cos_fused_kernel(
    const float* __restrict__ xs, const float* __restrict__ spk,
    float* __restrict__ out) {
  __shared__ float sA[2 * 128 * 64];  // 64 KB: double-buffered A tile
  float* scX = sA;                    // aliased: only used after the k-loop
  float* scY = sA + 128;

  const int tid = threadIdx.x;
  const int wave = tid >> 6;
  const int lane = tid & 63;

  // XCD swizzle (identical to verified R1; bijective over 512 blocks).
  const int id = blockIdx.x;
  const int xcd = id & 7;
  const int j = id >> 3;                    // 0..63
  const int pairIdx = xcd * 32 + (j >> 1);  // 0..255
  const int tn = j & 1;
  const int tm = pairIdx & 31;  // 128-row panel index, 0..31
  const int b = pairIdx >> 5;   // == xcd

  const int wm = wave >> 1;
  const int wn = wave & 1;
  const int quad = lane >> 4;
  const int l15 = lane & 15;
  const bool gramA = (wm == wn);

  const float* Abase = xs + ((size_t)b * TT + tm * 128) * DD;
  // Per-lane B source row base: row = tn*128 + wn*64 + in*16 + l15;
  // k offset = kt*64 + ks*32 + quad*8 (8 consecutive f32 per lane).
  const float* Bsrc = spk + ((size_t)b * SS + tn * 128 + wn * 64 + l15) * DD +
                      quad * 8;

  floatx4 acc[4][4];
#pragma unroll
  for (int i = 0; i < 4; i++)
#pragma unroll
    for (int jj = 0; jj < 4; jj++) acc[i][jj] = (floatx4){0.f, 0.f, 0.f, 0.f};
  floatx4 accG[4];  // gram accumulators (A-rows if wm==wn else B-rows)
#pragma unroll
  for (int i = 0; i < 4; i++) accG[i] = (floatx4){0.f, 0.f, 0.f, 0.f};

  // A staging map: 16B unit s = jj*256 + tid; row = s>>4 (16 units/row);
  // slot s&15 holds logical k-block (s&15) ^ (row&15)  [XOR-16 swizzle].
  int aoff[8];
#pragma unroll
  for (int jj = 0; jj < 8; jj++) {
    int s = jj * 256 + tid;
    int row = s >> 4;
    int blk = (s & 15) ^ (row & 15);
    aoff[jj] = row * DD + blk * 4;
  }

  // Prologue: stage kt=0 into buffer 0, full drain once.
#pragma unroll
  for (int jj = 0; jj < 8; jj++) {
    __builtin_amdgcn_global_load_lds(
        (const __attribute__((address_space(1))) unsigned int*)(Abase +
            aoff[jj]),
        (__attribute__((address_space(3))) unsigned int*)(sA +
            (jj * 256 + wave * 64) * 4),
        16, 0, 0);
  }
  __syncthreads();

  for (int kt = 0; kt < 8; ++kt) {
    const int cur = kt & 1;

    // B fragments for this kt: load spk f32 + convert in-register.
    // Issued FIRST (before the A DMA) as in verified R1.
    short8 breg[2][4];
#pragma unroll
    for (int ksl = 0; ksl < 2; ksl++)
#pragma unroll
      for (int in = 0; in < 4; in++) {
        const float* src = Bsrc + (size_t)in * 16 * DD + kt * 64 + ksl * 32;
        float4 f0 = *(const float4*)src;
        float4 f1 = *(const float4*)(src + 4);
        breg[ksl][in] = cvt8(f0, f1);
      }

    // Stage kt+1 into the other buffer; overlaps this kt's compute, drained
    // at the single syncthreads at the bottom.
    if (kt < 7) {
#pragma unroll
      for (int jj = 0; jj < 8; jj++) {
        __builtin_amdgcn_global_load_lds(
            (const __attribute__((address_space(1))) unsigned int*)(Abase +
                aoff[jj] + (kt + 1) * 64),
            (__attribute__((address_space(3))) unsigned int*)(sA +
                (cur ^ 1) * 8192 + (jj * 256 + wave * 64) * 4),
            16, 0, 0);
      }
    }

    const float* sAc = sA + cur * 8192;
#pragma unroll
    for (int ks = 0; ks < 2; ks++) {
      short8 af[4];
      const int b0s = ks * 8 + quad * 2;  // first 16B f32 block of A frag
#pragma unroll
      for (int im = 0; im < 4; im++) {
        int row = wm * 64 + im * 16 + l15;
        int s0 = b0s ^ (row & 15);
        int s1 = (b0s + 1) ^ (row & 15);
        float4 f0 = *(const float4*)(sAc + row * 64 + s0 * 4);
        float4 f1 = *(const float4*)(sAc + row * 64 + s1 * 4);
        af[im] = cvt8(f0, f1);
      }
#pragma unroll
      for (int im = 0; im < 4; im++)
#pragma unroll
        for (int in = 0; in < 4; in++)
          acc[im][in] = __builtin_amdgcn_mfma_f32_16x16x32_bf16(
              af[im], breg[ks][in], acc[im][in], 0, 0, 0);
      if (gramA) {
#pragma unroll
        for (int im = 0; im < 4; im++)
          accG[im] = __builtin_amdgcn_mfma_f32_16x16x32_bf16(
              af[im], af[im], accG[im], 0, 0, 0);
      } else {
#pragma unroll
        for (int in = 0; in < 4; in++)
          accG[in] = __builtin_amdgcn_mfma_f32_16x16x32_bf16(
              breg[ks][in], breg[ks][in], accG[in], 0, 0, 0);
      }
    }
    __syncthreads();  // single barrier per kt: syncs reads + drains DMA
  }

  // Extract gram diagonals -> inverse norms. C/D layout: col = l15,
  // row = quad*4 + r; diagonal element d: lane l15==d, quad==d>>2, r=d&3.
  // scX/scY alias sA: all sA reads finished before the loop's last barrier.
  if (quad == (l15 >> 2)) {
#pragma unroll
    for (int i = 0; i < 4; i++) {
      float inv = 1.0f / fmaxf(sqrtf(accG[i][l15 & 3]), 1e-8f);
      if (gramA)
        scX[wm * 64 + i * 16 + l15] = inv;  // waves (0,0),(1,1): rows 0..127
      else
        scY[wn * 64 + i * 16 + l15] = inv;  // waves (0,1),(1,0): cols 0..127
    }
  }
  __syncthreads();

  // Epilogue: apply cosine scales (dot * (1/||x||) * (1/||y||)).
  float* Obase = out + ((size_t)b * TT + tm * 128) * SS + tn * 128;
#pragma unroll
  for (int im = 0; im < 4; im++) {
#pragma unroll
    for (int in = 0; in < 4; in++) {
      int col = wn * 64 + in * 16 + l15;
      float yv = scY[col];
#pragma unroll
      for (int r = 0; r < 4; r++) {
        int row = wm * 64 + im * 16 + quad * 4 + r;
        Obase[row * SS + col] = acc[im][in][r] * scX[row] * yv;
      }
    }
  }
}

extern "C" void kernel_launch(void* const* d_in, const int* in_sizes, int n_in,
                              void* d_out, int out_size, void* d_ws,
                              size_t ws_size, hipStream_t stream) {
  const float* xs = (const float*)d_in[0];   // (8,4096,512) f32
  const float* spk = (const float*)d_in[1];  // (8,256,512) f32
  float* out = (float*)d_out;                // (8,4096,256) f32
  (void)d_ws;  // workspace intentionally UNUSED (avoid 2x256 MiB poison cost)
  (void)ws_size;

  hipLaunchKernelGGL(cos_fused_kernel, dim3(512), dim3(256), 0, stream, xs,
                     spk, out);
}

// Round 7
// 127.284 us; speedup vs baseline: 1.0201x; 1.0201x over previous
//
#include <hip/hip_runtime.h>
#include <hip/hip_bf16.h>

// Problem dims (fixed by the reference setup_inputs)
#define BB 8
#define TT 4096
#define SS 256
#define DD 512

typedef __attribute__((ext_vector_type(8))) short short8;
typedef __attribute__((ext_vector_type(4))) float floatx4;
typedef __attribute__((ext_vector_type(4))) int intx4;

// Packed RNE f32x2 -> bf16x2 (v_cvt_pk_bf16_f32 on gfx950).
__device__ inline int pk2(float a, float b) {
  __hip_bfloat162 h = __float22bfloat162_rn(make_float2(a, b));
  int r;
  __builtin_memcpy(&r, &h, 4);
  return r;
}

// Pack 8 consecutive-k f32 values into a bf16 MFMA fragment.
__device__ inline short8 cvt8(float4 f0, float4 f1) {
  intx4 p;
  p[0] = pk2(f0.x, f0.y);
  p[1] = pk2(f0.z, f0.w);
  p[2] = pk2(f1.x, f1.y);
  p[3] = pk2(f1.z, f1.w);
  return __builtin_bit_cast(short8, p);
}

// K1 (UNCHANGED, verified): pack spk (8,256,512) f32 -> bf16 in
// MFMA-FRAGMENT order so K2 loads each B fragment as ONE coalesced
// global_load_dwordx4 per wave. (ws poison fills are unconditional —
// R6 proved avoiding ws buys nothing, so using it is free.)
//   frag_idx = ((((b*2+tn)*2+wn)*8+kt)*2+ks)*4 + in   (512 shorts each)
//   lane l of frag: row = tn*128+wn*64+in*16+(l&15),
//                   k   = kt*64+ks*32+(l>>4)*8 .. +8
__global__ __launch_bounds__(256) void cos_packB_kernel(
    const float* __restrict__ spk, short* __restrict__ bp) {
  const int id = blockIdx.x;  // 512 blocks = (b, tn, wn, kt, ks)
  const int ks = id & 1;
  const int kt = (id >> 1) & 7;
  const int wn = (id >> 4) & 1;
  const int tn = (id >> 5) & 1;
  const int b = id >> 6;
  const int t = threadIdx.x;  // 256 = 4 in x 64 lane
  const int in = t >> 6;
  const int lane = t & 63;
  const int row = tn * 128 + wn * 64 + in * 16 + (lane & 15);
  const int k = kt * 64 + ks * 32 + (lane >> 4) * 8;
  const float* src = spk + ((size_t)(b * SS + row)) * DD + k;
  float4 f0 = *(const float4*)src;
  float4 f1 = *(const float4*)(src + 4);
  short8 o = cvt8(f0, f1);
  size_t frag = (size_t)((((b * 2 + tn) * 2 + wn) * 8 + kt) * 2 + ks) * 4 + in;
  *(short8*)(bp + frag * 512 + (size_t)lane * 8) = o;
}

// K2 round-7: BARRIER-FREE streaming scorer. R6 profile showed the fused
// family is latency-bound (1.3 TB/s, 18% occupancy, 70%+ idle), and the
// grid caps TLP at 2 waves/SIMD — so latency must be hidden by ILP.
// This version drops LDS/A-staging/barriers entirely:
//  - A: MFMA fragments loaded DIRECTLY from global (lane l -> row ..+l15,
//    k chunk quad*8; per instruction 16 aligned 64B segments — same
//    cache-line count as a coalesced 2 KB load; the wm-sharing wave pair
//    on the same CU turns the duplicate read into L1 hits). Pattern
//    numerically validated by R6's B path.
//  - B: verified K1-packed fragments, 4 coalesced 16B loads per step.
//  - 16 fully-unrolled steps with EXPLICIT 2-step-ahead prefetch into
//    3-deep rotating register buffers (all indices compile-time, rule
//    #20). ~24 VMEM ops in flight per wave, no vmcnt(0) anywhere in the
//    loop. VGPR ~190 + acc in AGPRs — free at 2 waves/SIMD.
//  - Same XCD swizzle, gram-MFMA norms, accumulation order as verified
//    R1 -> bit-identical output.
__global__ __launch_bounds__(256) void cos_fused_kernel(
    const float* __restrict__ xs, const short* __restrict__ bp,
    float* __restrict__ out) {
  __shared__ float scX[128];
  __shared__ float scY[128];

  const int tid = threadIdx.x;
  const int wave = tid >> 6;
  const int lane = tid & 63;

  // XCD swizzle (identical to verified R1; bijective over 512 blocks).
  const int id = blockIdx.x;
  const int xcd = id & 7;
  const int j = id >> 3;                    // 0..63
  const int pairIdx = xcd * 32 + (j >> 1);  // 0..255
  const int tn = j & 1;
  const int tm = pairIdx & 31;  // 128-row panel index, 0..31
  const int b = pairIdx >> 5;   // == xcd

  const int wm = wave >> 1;
  const int wn = wave & 1;
  const int quad = lane >> 4;
  const int l15 = lane & 15;
  const bool gramA = (wm == wn);

  // Per-lane A fragment row pointers: lane holds row ...+l15, k chunk
  // quad*8..+8 (f0 at +0, f1 at +4) — element-for-element the MFMA A
  // fragment layout (same mapping as K1's B fragments).
  const float* Arow[4];
#pragma unroll
  for (int im = 0; im < 4; im++)
    Arow[im] = xs +
               ((size_t)b * TT + tm * 128 + wm * 64 + im * 16 + l15) * DD +
               quad * 8;

  // Per-wave, per-lane B fragment base (shorts). K1 layout unchanged.
  const short* Bw =
      bp + (size_t)((b * 2 + tn) * 2 + wn) * 32768 + (size_t)lane * 8;

  floatx4 acc[4][4];
#pragma unroll
  for (int i = 0; i < 4; i++)
#pragma unroll
    for (int jj = 0; jj < 4; jj++) acc[i][jj] = (floatx4){0.f, 0.f, 0.f, 0.f};
  floatx4 accG[4];  // gram accumulators (A-rows if wm==wn else B-rows)
#pragma unroll
  for (int i = 0; i < 4; i++) accG[i] = (floatx4){0.f, 0.f, 0.f, 0.f};

  // Rotating register stage buffers; step s = kt*2 + ks (16 steps).
  // All indices compile-time under full unroll.
  float4 abuf[3][8];
  short8 bbuf[3][4];

#define LOADA(S)                                                        \
  do {                                                                  \
    _Pragma("unroll") for (int im_ = 0; im_ < 4; im_++) {               \
      const float* p_ = Arow[im_] + ((S) >> 1) * 64 + ((S) & 1) * 32;   \
      abuf[(S) % 3][im_ * 2] = *(const float4*)p_;                      \
      abuf[(S) % 3][im_ * 2 + 1] = *(const float4*)(p_ + 4);            \
    }                                                                   \
  } while (0)

#define LOADB(S)                                                        \
  do {                                                                  \
    const short* q_ = Bw + ((S) >> 1) * 4096 + ((S) & 1) * 2048;        \
    _Pragma("unroll") for (int in_ = 0; in_ < 4; in_++)                 \
      bbuf[(S) % 3][in_] = *(const short8*)(q_ + in_ * 512);            \
  } while (0)

  // Prologue: steps 0 and 1 in flight.
  LOADA(0);
  LOADB(0);
  LOADA(1);
  LOADB(1);

#pragma unroll
  for (int s = 0; s < 16; ++s) {
    // Prefetch 2 steps ahead — never drained by a barrier.
    if (s + 2 < 16) {
      LOADA(s + 2);
      LOADB(s + 2);
    }

    short8 af[4];
#pragma unroll
    for (int im = 0; im < 4; im++)
      af[im] = cvt8(abuf[s % 3][im * 2], abuf[s % 3][im * 2 + 1]);

#pragma unroll
    for (int im = 0; im < 4; im++)
#pragma unroll
      for (int in = 0; in < 4; in++)
        acc[im][in] = __builtin_amdgcn_mfma_f32_16x16x32_bf16(
            af[im], bbuf[s % 3][in], acc[im][in], 0, 0, 0);
    if (gramA) {
#pragma unroll
      for (int im = 0; im < 4; im++)
        accG[im] = __builtin_amdgcn_mfma_f32_16x16x32_bf16(
            af[im], af[im], accG[im], 0, 0, 0);
    } else {
#pragma unroll
      for (int in = 0; in < 4; in++)
        accG[in] = __builtin_amdgcn_mfma_f32_16x16x32_bf16(
            bbuf[s % 3][in], bbuf[s % 3][in], accG[in], 0, 0, 0);
    }
  }
#undef LOADA
#undef LOADB

  // Extract gram diagonals -> inverse norms. C/D layout: col = l15,
  // row = quad*4 + r; diagonal element d: lane l15==d, quad==d>>2, r=d&3.
  if (quad == (l15 >> 2)) {
#pragma unroll
    for (int i = 0; i < 4; i++) {
      float inv = 1.0f / fmaxf(sqrtf(accG[i][l15 & 3]), 1e-8f);
      if (gramA)
        scX[wm * 64 + i * 16 + l15] = inv;  // waves (0,0),(1,1): rows 0..127
      else
        scY[wn * 64 + i * 16 + l15] = inv;  // waves (0,1),(1,0): cols 0..127
    }
  }
  __syncthreads();  // the ONLY barrier: norm exchange before epilogue

  // Epilogue: apply cosine scales (dot * (1/||x||) * (1/||y||)).
  float* Obase = out + ((size_t)b * TT + tm * 128) * SS + tn * 128;
#pragma unroll
  for (int im = 0; im < 4; im++) {
#pragma unroll
    for (int in = 0; in < 4; in++) {
      int col = wn * 64 + in * 16 + l15;
      float yv = scY[col];
#pragma unroll
      for (int r = 0; r < 4; r++) {
        int row = wm * 64 + im * 16 + quad * 4 + r;
        Obase[row * SS + col] = acc[im][in][r] * scX[row] * yv;
      }
    }
  }
}

extern "C" void kernel_launch(void* const* d_in, const int* in_sizes, int n_in,
                              void* d_out, int out_size, void* d_ws,
                              size_t ws_size, hipStream_t stream) {
  const float* xs = (const float*)d_in[0];   // (8,4096,512) f32
  const float* spk = (const float*)d_in[1];  // (8,256,512) f32
  float* out = (float*)d_out;                // (8,4096,256) f32
  short* bp = (short*)d_ws;                  // 2 MB packed bf16 B (frag order)

  hipLaunchKernelGGL(cos_packB_kernel, dim3(512), dim3(256), 0, stream, spk,
                     bp);
  hipLaunchKernelGGL(cos_fused_kernel, dim3(512), dim3(256), 0, stream, xs,
                     bp, out);
}

// Round 8
// 124.872 us; speedup vs baseline: 1.0398x; 1.0193x over previous
//
#include <hip/hip_runtime.h>
#include <hip/hip_bf16.h>

// Problem dims (fixed by the reference setup_inputs)
#define BB 8
#define TT 4096
#define SS 256
#define DD 512

typedef __attribute__((ext_vector_type(8))) short short8;
typedef __attribute__((ext_vector_type(4))) float floatx4;
typedef __attribute__((ext_vector_type(4))) int intx4;

// Packed RNE f32x2 -> bf16x2 (v_cvt_pk_bf16_f32 on gfx950).
__device__ inline int pk2(float a, float b) {
  __hip_bfloat162 h = __float22bfloat162_rn(make_float2(a, b));
  int r;
  __builtin_memcpy(&r, &h, 4);
  return r;
}

// Pack 8 consecutive-k f32 values into a bf16 MFMA fragment.
__device__ inline short8 cvt8(float4 f0, float4 f1) {
  intx4 p;
  p[0] = pk2(f0.x, f0.y);
  p[1] = pk2(f0.z, f0.w);
  p[2] = pk2(f1.x, f1.y);
  p[3] = pk2(f1.z, f1.w);
  return __builtin_bit_cast(short8, p);
}

// K1 (UNCHANGED, verified): pack spk (8,256,512) f32 -> bf16 in
// MFMA-FRAGMENT order so K2 loads each B fragment as ONE coalesced
// global_load_dwordx4 per wave. (R6 proved ws poison is unconditional,
// so using ws is free.)
//   frag_idx = ((((b*2+tn)*2+wn)*8+kt)*2+ks)*4 + in   (512 shorts each)
//   lane l of frag: row = tn*128+wn*64+in*16+(l&15),
//                   k   = kt*64+ks*32+(l>>4)*8 .. +8
__global__ __launch_bounds__(256) void cos_packB_kernel(
    const float* __restrict__ spk, short* __restrict__ bp) {
  const int id = blockIdx.x;  // 512 blocks = (b, tn, wn, kt, ks)
  const int ks = id & 1;
  const int kt = (id >> 1) & 7;
  const int wn = (id >> 4) & 1;
  const int tn = (id >> 5) & 1;
  const int b = id >> 6;
  const int t = threadIdx.x;  // 256 = 4 in x 64 lane
  const int in = t >> 6;
  const int lane = t & 63;
  const int row = tn * 128 + wn * 64 + in * 16 + (lane & 15);
  const int k = kt * 64 + ks * 32 + (lane >> 4) * 8;
  const float* src = spk + ((size_t)(b * SS + row)) * DD + k;
  float4 f0 = *(const float4*)src;
  float4 f1 = *(const float4*)(src + 4);
  short8 o = cvt8(f0, f1);
  size_t frag = (size_t)((((b * 2 + tn) * 2 + wn) * 8 + kt) * 2 + ks) * 4 + in;
  *(short8*)(bp + frag * 512 + (size_t)lane * 8) = o;
}

// K2 round-8: ZERO-BARRIER k-loop via WAVE-PRIVATE LDS staging.
// R1's limiter theory: every __syncthreads drains vmcnt(0) and convoys
// all 4 waves — no stage ever in flight across compute. Here each wave
// DMA-stages its OWN 64 A-rows into its OWN LDS region (4 waves x 2 bufs
// x 8 KB = 64 KB), BK=32, 16 fully-unrolled steps, depth-1 stage + B
// 2-ahead in registers, per-wave counted s_waitcnt vmcnt(16/12/8/4) —
// never 0, no s_barrier until the norm exchange. Waves drift freely: 8
// independent pipelines per CU instead of 2 convoys. A-panel duplicate
// (wn pair) is an L2 hit. Staging/read map = R4's proven XOR-8 pattern;
// gram/epilogue/accumulation order identical to verified R1.
__global__ __launch_bounds__(256) void cos_fused_kernel(
    const float* __restrict__ xs, const short* __restrict__ bp,
    float* __restrict__ out) {
  __shared__ float sA[16384];  // 64 KB: 4 waves x 2 bufs x (64 rows x 32 k)
  float* scX = sA;             // aliased: only used after the k-loop
  float* scY = sA + 128;

  const int tid = threadIdx.x;
  const int wave = tid >> 6;
  const int lane = tid & 63;

  // XCD swizzle (identical to verified R1; bijective over 512 blocks).
  const int id = blockIdx.x;
  const int xcd = id & 7;
  const int j = id >> 3;                    // 0..63
  const int pairIdx = xcd * 32 + (j >> 1);  // 0..255
  const int tn = j & 1;
  const int tm = pairIdx & 31;  // 128-row panel index, 0..31
  const int b = pairIdx >> 5;   // == xcd

  const int wm = wave >> 1;
  const int wn = wave & 1;
  const int quad = lane >> 4;
  const int l15 = lane & 15;
  const bool gramA = (wm == wn);

  // Wave's 64 A rows (wm half of the 128-row panel).
  const float* Aw = xs + ((size_t)b * TT + tm * 128 + wm * 64) * DD;
  float* ldsW = sA + wave * 4096;  // wave-private LDS (floats)

  // Per-wave, per-lane B fragment base (shorts). K1 layout unchanged.
  const short* Bw =
      bp + (size_t)((b * 2 + tn) * 2 + wn) * 32768 + (size_t)lane * 8;

  floatx4 acc[4][4];
#pragma unroll
  for (int i = 0; i < 4; i++)
#pragma unroll
    for (int jj = 0; jj < 4; jj++) acc[i][jj] = (floatx4){0.f, 0.f, 0.f, 0.f};
  floatx4 accG[4];  // gram accumulators (A-rows if wm==wn else B-rows)
#pragma unroll
  for (int i = 0; i < 4; i++) accG[i] = (floatx4){0.f, 0.f, 0.f, 0.f};

  // Per-wave staging map (R4's verified XOR-8): unit u = o*64 + lane;
  // lrow = u>>3 (8 units/row), stored slot u&7 holds logical k-block
  // (u&7) ^ (lrow&7). LDS float offset of unit u = u*4 = lrow*32 + slot*4.
  int soff[8];
#pragma unroll
  for (int o = 0; o < 8; o++) {
    int u = o * 64 + lane;
    int lrow = u >> 3;
    int kblk = (u & 7) ^ (lrow & 7);
    soff[o] = lrow * DD + kblk * 4;
  }

// Stage one BK=32 step (8 KB/wave, 8 DMA ops) into buf (KT)&1.
#define STAGE(KT)                                                          \
  do {                                                                     \
    _Pragma("unroll") for (int o_ = 0; o_ < 8; o_++) {                     \
      __builtin_amdgcn_global_load_lds(                                    \
          (const __attribute__((address_space(1))) unsigned int*)(Aw +     \
              soff[o_] + (KT) * 32),                                       \
          (__attribute__((address_space(3))) unsigned int*)(ldsW +         \
              ((KT) & 1) * 2048 + o_ * 256),                               \
          16, 0, 0);                                                       \
    }                                                                      \
  } while (0)

// B fragments for step KT -> bbuf[(KT)%3] (4 coalesced 16B loads).
#define LOADB(KT)                                                          \
  do {                                                                     \
    const short* q_ = Bw + ((KT) >> 1) * 4096 + ((KT) & 1) * 2048;         \
    _Pragma("unroll") for (int in_ = 0; in_ < 4; in_++)                    \
      bbuf[(KT) % 3][in_] = *(const short8*)(q_ + in_ * 512);              \
  } while (0)

#define WAITVM(N) asm volatile("s_waitcnt vmcnt(" #N ")" ::: "memory")

  short8 bbuf[3][4];  // statically indexed under full unroll (rule #20)

  // Prologue: B0, B1, stage 0 and 1. (Issue order fixed by "memory" asm.)
  LOADB(0);
  LOADB(1);
  STAGE(0);
  STAGE(1);

#pragma unroll
  for (int kt = 0; kt < 16; ++kt) {
    // 1) Wait for stage(kt) WITHOUT draining later prefetch. Tail counts
    //    (in-order vmcnt semantics), issue order: B0 B1 S0 S1 | iter j:
    //    reads, [S(j+2)], [B(j+2)]:
    //    kt=0: after S0 = S1(8)               -> 8
    //    kt=1: after S1 = S2(8)+B2(4)         -> 12
    //    kt 2..14: B(kt)(4)+S(kt+1)(8)+B(kt+1)(4) -> 16
    //    kt=15: after S15 = B15(4)            -> 4
    if (kt == 0)
      WAITVM(8);
    else if (kt == 1)
      WAITVM(12);
    else if (kt == 15)
      WAITVM(4);
    else
      WAITVM(16);
    __builtin_amdgcn_sched_barrier(0);

    // 2) LDS -> registers (8 x ds_read_b128, XOR-8 descrambled).
    float4 f0v[4], f1v[4];
    const float* base = ldsW + (kt & 1) * 2048;
#pragma unroll
    for (int im = 0; im < 4; im++) {
      int lrow = im * 16 + l15;
      int s0 = (quad * 2) ^ (l15 & 7);
      int s1 = (quad * 2 + 1) ^ (l15 & 7);
      f0v[im] = *(const float4*)(base + lrow * 32 + s0 * 4);
      f1v[im] = *(const float4*)(base + lrow * 32 + s1 * 4);
    }
    // 3) All reads of buf (kt&1) complete before re-staging it.
    asm volatile("s_waitcnt lgkmcnt(0)" ::: "memory");
    __builtin_amdgcn_sched_barrier(0);

    // 4) Re-stage this buffer with step kt+2; prefetch B(kt+2).
    if (kt + 2 < 16) {
      STAGE(kt + 2);
      LOADB(kt + 2);
    }

    // 5) Convert + MFMA (compiler waits bbuf's own vmcnt; issued 2 iters
    //    ago so the wait never drains the fresh stage).
    short8 af[4];
#pragma unroll
    for (int im = 0; im < 4; im++) af[im] = cvt8(f0v[im], f1v[im]);

#pragma unroll
    for (int im = 0; im < 4; im++)
#pragma unroll
      for (int in = 0; in < 4; in++)
        acc[im][in] = __builtin_amdgcn_mfma_f32_16x16x32_bf16(
            af[im], bbuf[kt % 3][in], acc[im][in], 0, 0, 0);
    if (gramA) {
#pragma unroll
      for (int im = 0; im < 4; im++)
        accG[im] = __builtin_amdgcn_mfma_f32_16x16x32_bf16(
            af[im], af[im], accG[im], 0, 0, 0);
    } else {
#pragma unroll
      for (int in = 0; in < 4; in++)
        accG[in] = __builtin_amdgcn_mfma_f32_16x16x32_bf16(
            bbuf[kt % 3][in], bbuf[kt % 3][in], accG[in], 0, 0, 0);
    }
  }
#undef STAGE
#undef LOADB
#undef WAITVM

  __syncthreads();  // first barrier: all private-LDS activity done

  // Extract gram diagonals -> inverse norms. C/D layout: col = l15,
  // row = quad*4 + r; diagonal element d: lane l15==d, quad==d>>2, r=d&3.
  if (quad == (l15 >> 2)) {
#pragma unroll
    for (int i = 0; i < 4; i++) {
      float inv = 1.0f / fmaxf(sqrtf(accG[i][l15 & 3]), 1e-8f);
      if (gramA)
        scX[wm * 64 + i * 16 + l15] = inv;  // waves (0,0),(1,1): rows 0..127
      else
        scY[wn * 64 + i * 16 + l15] = inv;  // waves (0,1),(1,0): cols 0..127
    }
  }
  __syncthreads();

  // Epilogue: apply cosine scales (dot * (1/||x||) * (1/||y||)).
  float* Obase = out + ((size_t)b * TT + tm * 128) * SS + tn * 128;
#pragma unroll
  for (int im = 0; im < 4; im++) {
#pragma unroll
    for (int in = 0; in < 4; in++) {
      int col = wn * 64 + in * 16 + l15;
      float yv = scY[col];
#pragma unroll
      for (int r = 0; r < 4; r++) {
        int row = wm * 64 + im * 16 + quad * 4 + r;
        Obase[row * SS + col] = acc[im][in][r] * scX[row] * yv;
      }
    }
  }
}

extern "C" void kernel_launch(void* const* d_in, const int* in_sizes, int n_in,
                              void* d_out, int out_size, void* d_ws,
                              size_t ws_size, hipStream_t stream) {
  const float* xs = (const float*)d_in[0];   // (8,4096,512) f32
  const float* spk = (const float*)d_in[1];  // (8,256,512) f32
  float* out = (float*)d_out;                // (8,4096,256) f32
  short* bp = (short*)d_ws;                  // 2 MB packed bf16 B (frag order)

  hipLaunchKernelGGL(cos_packB_kernel, dim3(512), dim3(256), 0, stream, spk,
                     bp);
  hipLaunchKernelGGL(cos_fused_kernel, dim3(512), dim3(256), 0, stream, xs,
                     bp, out);
}

// Round 9
// 118.329 us; speedup vs baseline: 1.0972x; 1.0553x over previous
//
#include <hip/hip_runtime.h>
#include <hip/hip_bf16.h>

// Problem dims (fixed by the reference setup_inputs)
#define BB 8
#define TT 4096
#define SS 256
#define DD 512

typedef __attribute__((ext_vector_type(8))) short short8;
typedef __attribute__((ext_vector_type(4))) float floatx4;
typedef __attribute__((ext_vector_type(4))) int intx4;

// Packed RNE f32x2 -> bf16x2 (v_cvt_pk_bf16_f32 on gfx950).
__device__ inline int pk2(float a, float b) {
  __hip_bfloat162 h = __float22bfloat162_rn(make_float2(a, b));
  int r;
  __builtin_memcpy(&r, &h, 4);
  return r;
}

// Pack 8 consecutive-k f32 values into a bf16 MFMA fragment.
__device__ inline short8 cvt8(float4 f0, float4 f1) {
  intx4 p;
  p[0] = pk2(f0.x, f0.y);
  p[1] = pk2(f0.z, f0.w);
  p[2] = pk2(f1.x, f1.y);
  p[3] = pk2(f1.z, f1.w);
  return __builtin_bit_cast(short8, p);
}

// K1: pack spk (8,256,512) f32 -> bf16 in MFMA-FRAGMENT order so the fused
// kernel loads each B fragment as ONE coalesced global_load_dwordx4 per wave
// (64 lanes x 16 B = 1 KiB contiguous).
//   frag_idx = ((((b*2+tn)*2+wn)*8+kt)*2+ks)*4 + in   (512 shorts each)
//   lane l of frag: row = tn*128+wn*64+in*16+(l&15),
//                   k   = kt*64+ks*32+(l>>4)*8 .. +8
__global__ __launch_bounds__(256) void cos_packB_kernel(
    const float* __restrict__ spk, short* __restrict__ bp) {
  const int id = blockIdx.x;  // 512 blocks = (b, tn, wn, kt, ks)
  const int ks = id & 1;
  const int kt = (id >> 1) & 7;
  const int wn = (id >> 4) & 1;
  const int tn = (id >> 5) & 1;
  const int b = id >> 6;
  const int t = threadIdx.x;  // 256 = 4 in x 64 lane
  const int in = t >> 6;
  const int lane = t & 63;
  const int row = tn * 128 + wn * 64 + in * 16 + (lane & 15);
  const int k = kt * 64 + ks * 32 + (lane >> 4) * 8;
  const float* src = spk + ((size_t)(b * SS + row)) * DD + k;
  float4 f0 = *(const float4*)src;
  float4 f1 = *(const float4*)(src + 4);
  short8 o = cvt8(f0, f1);
  size_t frag = (size_t)((((b * 2 + tn) * 2 + wn) * 8 + kt) * 2 + ks) * 4 + in;
  *(short8*)(bp + frag * 512 + (size_t)lane * 8) = o;
}

// K2: fused cosine scorer (VERIFIED BEST, round-1 structure, 116.97 us):
//  - A: f32, BK=64, async global_load_lds width=16, XOR-16 swizzle
//    (conflict-free), DOUBLE-BUFFERED (2x32 KB) with ONE barrier per kt:
//    issue stage(kt+1) -> compute(kt) -> syncthreads.
//  - B: fragment-ordered bf16 loaded straight to registers (coalesced 1 KiB
//    per wave per frag). Issued BEFORE the A-DMA each kt so the compiler's
//    vmcnt wait for B (oldest-first) does not drain the A stage.
//  - XCD swizzle: id%8 = XCD; both tn halves of one (b,tm) A panel run
//    adjacently on the same XCD; each XCD owns exactly one batch b.
//  - scX/scY alias sA after the k-loop -> LDS stays at exactly 64 KB.
// Eight structural variants (counted-vmcnt pipeline, wave-private
// zero-barrier staging, register-only streaming, in-kernel B pack, 8-wave
// blocks, 64-row tiles) all measured equal or worse (117-130 us window);
// this structure is the empirical floor. Remaining window is dominated by
// the harness's unconditional 2x256 MiB workspace poison fills (~83 us).
__global__ __launch_bounds__(256) void cos_fused_kernel(
    const float* __restrict__ xs, const short* __restrict__ bp,
    float* __restrict__ out) {
  __shared__ float sA[2 * 128 * 64];  // 64 KB: double-buffered A tile
  float* scX = sA;                    // aliased: only used after the k-loop
  float* scY = sA + 128;

  const int tid = threadIdx.x;
  const int wave = tid >> 6;
  const int lane = tid & 63;

  // XCD-pair swizzle (bijective over 512 blocks).
  const int id = blockIdx.x;
  const int xcd = id & 7;
  const int j = id >> 3;                     // 0..63 (per-XCD slot)
  const int pairIdx = xcd * 32 + (j >> 1);   // 0..255
  const int tn = j & 1;                      // tn pair adjacent on same XCD
  const int tm = pairIdx & 31;
  const int b = pairIdx >> 5;                // XCD x owns batch b == x

  const int wm = wave >> 1;
  const int wn = wave & 1;
  const int quad = lane >> 4;
  const int l15 = lane & 15;
  const bool gramA = (wm == wn);

  const float* Abase = xs + ((size_t)b * TT + tm * 128) * DD;
  // Per-wave, per-lane B fragment base (shorts).
  const short* Bw =
      bp + (size_t)((b * 2 + tn) * 2 + wn) * 32768 + (size_t)lane * 8;

  floatx4 acc[4][4];
#pragma unroll
  for (int i = 0; i < 4; i++)
#pragma unroll
    for (int jj = 0; jj < 4; jj++) acc[i][jj] = (floatx4){0.f, 0.f, 0.f, 0.f};
  floatx4 accG[4];  // gram accumulators (A-rows if wm==wn else B-rows)
#pragma unroll
  for (int i = 0; i < 4; i++) accG[i] = (floatx4){0.f, 0.f, 0.f, 0.f};

  // A staging map: 16B unit s = jj*256 + tid; row = s>>4; slot s&15 holds
  // logical k-block (s&15) ^ (row&15)  [XOR-16 swizzle].
  int aoff[8];
#pragma unroll
  for (int jj = 0; jj < 8; jj++) {
    int s = jj * 256 + tid;
    int row = s >> 4;
    int blk = (s & 15) ^ (row & 15);
    aoff[jj] = row * DD + blk * 4;
  }

  // Prologue: stage kt=0 into buffer 0, full drain once.
#pragma unroll
  for (int jj = 0; jj < 8; jj++) {
    __builtin_amdgcn_global_load_lds(
        (const __attribute__((address_space(1))) unsigned int*)(Abase +
            aoff[jj]),
        (__attribute__((address_space(3))) unsigned int*)(sA +
            (jj * 256 + wave * 64) * 4),
        16, 0, 0);
  }
  __syncthreads();

  for (int kt = 0; kt < 8; ++kt) {
    const int cur = kt & 1;

    // B fragments for this kt -> registers. Issued FIRST so the vmcnt wait
    // on them (oldest-first) completes without draining the A DMA below.
    short8 breg[2][4];
    const short* Bkt = Bw + kt * 4096;
#pragma unroll
    for (int ksl = 0; ksl < 2; ksl++)
#pragma unroll
      for (int in = 0; in < 4; in++)
        breg[ksl][in] = *(const short8*)(Bkt + ksl * 2048 + in * 512);

    // Stage kt+1 into the other buffer; overlaps this kt's compute, drained
    // only at the single syncthreads at the bottom.
    if (kt < 7) {
#pragma unroll
      for (int jj = 0; jj < 8; jj++) {
        __builtin_amdgcn_global_load_lds(
            (const __attribute__((address_space(1))) unsigned int*)(Abase +
                aoff[jj] + (kt + 1) * 64),
            (__attribute__((address_space(3))) unsigned int*)(sA +
                (cur ^ 1) * 8192 + (jj * 256 + wave * 64) * 4),
            16, 0, 0);
      }
    }

    const float* sAc = sA + cur * 8192;
#pragma unroll
    for (int ks = 0; ks < 2; ks++) {
      short8 af[4];
      const int b0s = ks * 8 + quad * 2;  // first 16B f32 block of A frag
#pragma unroll
      for (int im = 0; im < 4; im++) {
        int row = wm * 64 + im * 16 + l15;
        int s0 = b0s ^ (row & 15);
        int s1 = (b0s + 1) ^ (row & 15);
        float4 f0 = *(const float4*)(sAc + row * 64 + s0 * 4);
        float4 f1 = *(const float4*)(sAc + row * 64 + s1 * 4);
        af[im] = cvt8(f0, f1);
      }
#pragma unroll
      for (int im = 0; im < 4; im++)
#pragma unroll
        for (int in = 0; in < 4; in++)
          acc[im][in] = __builtin_amdgcn_mfma_f32_16x16x32_bf16(
              af[im], breg[ks][in], acc[im][in], 0, 0, 0);
      if (gramA) {
#pragma unroll
        for (int im = 0; im < 4; im++)
          accG[im] = __builtin_amdgcn_mfma_f32_16x16x32_bf16(
              af[im], af[im], accG[im], 0, 0, 0);
      } else {
#pragma unroll
        for (int in = 0; in < 4; in++)
          accG[in] = __builtin_amdgcn_mfma_f32_16x16x32_bf16(
              breg[ks][in], breg[ks][in], accG[in], 0, 0, 0);
      }
    }
    __syncthreads();  // single barrier per kt: syncs reads + drains DMA
  }

  // Extract gram diagonals -> inverse norms. C/D layout: col = l15,
  // row = quad*4 + r; diagonal element d: lane with l15==d, quad==d>>2,
  // reg r = d&3. scX/scY alias sA: all sA reads finished before the
  // loop's last barrier.
  if (quad == (l15 >> 2)) {
#pragma unroll
    for (int i = 0; i < 4; i++) {
      float inv = 1.0f / fmaxf(sqrtf(accG[i][l15 & 3]), 1e-8f);
      if (gramA)
        scX[wm * 64 + i * 16 + l15] = inv;  // waves (0,0),(1,1): rows 0..127
      else
        scY[wn * 64 + i * 16 + l15] = inv;  // waves (0,1),(1,0): cols 0..127
    }
  }
  __syncthreads();

  // Epilogue: apply cosine scales (dot * (1/||x||) * (1/||y||)).
  float* Obase = out + ((size_t)b * TT + tm * 128) * SS + tn * 128;
#pragma unroll
  for (int im = 0; im < 4; im++) {
#pragma unroll
    for (int in = 0; in < 4; in++) {
      int col = wn * 64 + in * 16 + l15;
      float yv = scY[col];
#pragma unroll
      for (int r = 0; r < 4; r++) {
        int row = wm * 64 + im * 16 + quad * 4 + r;
        Obase[row * SS + col] = acc[im][in][r] * scX[row] * yv;
      }
    }
  }
}

extern "C" void kernel_launch(void* const* d_in, const int* in_sizes, int n_in,
                              void* d_out, int out_size, void* d_ws,
                              size_t ws_size, hipStream_t stream) {
  const float* xs = (const float*)d_in[0];   // (8,4096,512) f32
  const float* spk = (const float*)d_in[1];  // (8,256,512) f32
  float* out = (float*)d_out;                // (8,4096,256) f32
  short* bp = (short*)d_ws;                  // 2 MB packed bf16 B (frag order)

  hipLaunchKernelGGL(cos_packB_kernel, dim3(512), dim3(256), 0, stream, spk,
                     bp);
  hipLaunchKernelGGL(cos_fused_kernel, dim3(512), dim3(256), 0, stream, xs,
                     bp, out);
}